// Round 2
// baseline (4082.927 us; speedup 1.0000x reference)
//
#include <hip/hip_runtime.h>
#include <math.h>

#define D_IN  768
#define NHD   8
#define HDIM  96
#define HID   768
#define UPD   1536
#define FUSED 2320
#define KER   4
#define CS    64
#define NCH   64
#define SB    4096
#define BB    2
#define NROW  (BB*SB)          // 8192
#define NCHUNK (BB*NHD*NCH)    // 1024

// ---------------- LayerNorm over D_IN (input) ----------------
__global__ __launch_bounds__(256) void ln_in_kernel(
    const float* __restrict__ x, const float* __restrict__ w,
    const float* __restrict__ b, float* __restrict__ out)
{
    int row = blockIdx.x;
    size_t base = (size_t)row * D_IN;
    int c0 = threadIdx.x, c1 = threadIdx.x + 256, c2 = threadIdx.x + 512;
    float v0 = x[base + c0], v1 = x[base + c1], v2 = x[base + c2];
    float s = v0 + v1 + v2;
    float ss = v0*v0 + v1*v1 + v2*v2;
    for (int off = 32; off; off >>= 1) { s += __shfl_xor(s, off); ss += __shfl_xor(ss, off); }
    __shared__ float red[8];
    int wid = threadIdx.x >> 6;
    if ((threadIdx.x & 63) == 0) { red[wid] = s; red[4 + wid] = ss; }
    __syncthreads();
    s = red[0] + red[1] + red[2] + red[3];
    ss = red[4] + red[5] + red[6] + red[7];
    float mean = s * (1.f / D_IN);
    float var = ss * (1.f / D_IN) - mean * mean;
    float inv = rsqrtf(var + 1e-6f);
    out[base + c0] = (v0 - mean) * inv * w[c0] + b[c0];
    out[base + c1] = (v1 - mean) * inv * w[c1] + b[c1];
    out[base + c2] = (v2 - mean) * inv * w[c2] + b[c2];
}

// ---------------- generic tiled fp32 GEMM: C = act(A@B + bias) (+resid) ----
// A: [M,K] row-major, B: [K,N] row-major. act: 0=none, 1=sigmoid
__global__ __launch_bounds__(256) void gemm_kernel(
    const float* __restrict__ A, const float* __restrict__ B,
    const float* __restrict__ bias, const float* __restrict__ resid,
    float* __restrict__ C, int M, int N, int K, int act)
{
    __shared__ float As[16][68];
    __shared__ float Bs[16][64];
    int tx = threadIdx.x & 15;
    int ty = threadIdx.x >> 4;
    int m0 = blockIdx.y * 64;
    int n0 = blockIdx.x * 64;
    float acc[4][4] = {};
    for (int k0 = 0; k0 < K; k0 += 16) {
        #pragma unroll
        for (int it = 0; it < 4; ++it) {
            int idx = threadIdx.x + it * 256;
            int r = idx >> 4, c = idx & 15;
            As[c][r] = A[(size_t)(m0 + r) * K + k0 + c];
        }
        #pragma unroll
        for (int it = 0; it < 4; ++it) {
            int idx = threadIdx.x + it * 256;
            int r = idx >> 6, c = idx & 63;
            int n = n0 + c;
            Bs[r][c] = (n < N) ? B[(size_t)(k0 + r) * N + n] : 0.f;
        }
        __syncthreads();
        #pragma unroll
        for (int kk = 0; kk < 16; ++kk) {
            float a[4], bb[4];
            #pragma unroll
            for (int i = 0; i < 4; ++i) a[i] = As[kk][ty * 4 + i];
            #pragma unroll
            for (int j = 0; j < 4; ++j) bb[j] = Bs[kk][tx * 4 + j];
            #pragma unroll
            for (int i = 0; i < 4; ++i)
                #pragma unroll
                for (int j = 0; j < 4; ++j) acc[i][j] += a[i] * bb[j];
        }
        __syncthreads();
    }
    #pragma unroll
    for (int i = 0; i < 4; ++i) {
        int m = m0 + ty * 4 + i;
        #pragma unroll
        for (int j = 0; j < 4; ++j) {
            int n = n0 + tx * 4 + j;
            if (n < N) {
                float v = acc[i][j] + bias[n];
                if (act == 1) v = 1.f / (1.f + expf(-v));
                if (resid) v += resid[(size_t)m * N + n];
                C[(size_t)m * N + n] = v;
            }
        }
    }
}

// ---------------- causal depthwise conv (shared scalar kernel) + silu ------
__global__ void conv_kernel(const float* __restrict__ xt, const float* __restrict__ cw,
                            const float* __restrict__ cb, float* __restrict__ xc)
{
    size_t idx = (size_t)blockIdx.x * blockDim.x + threadIdx.x;
    if (idx >= (size_t)NROW * UPD) return;
    int ch = idx % UPD;
    int s = (int)((idx / UPD) % SB);
    int b = (int)(idx / ((size_t)UPD * SB));
    float acc = cb[0];
    #pragma unroll
    for (int j = 0; j < KER; ++j) {
        int sj = s - (KER - 1) + j;
        if (sj >= 0) acc += cw[j] * xt[((size_t)b * SB + sj) * UPD + ch];
    }
    xc[idx] = acc / (1.f + expf(-acc));   // silu
}

// ---------------- gates: softcap, exp-normalize, in-chunk log-forget scan --
__global__ __launch_bounds__(64) void gates_kernel(
    const float* __restrict__ proj, float* __restrict__ lf,
    float* __restrict__ ic, float* __restrict__ wC)
{
    int cid = blockIdx.x;
    int l = threadIdx.x;
    int b = cid >> 9;
    int nh = (cid >> 6) & 7;
    int c = cid & 63;
    int s = c * CS + l;
    size_t row = ((size_t)b * SB + s) * FUSED;
    float ip = proj[row + nh];
    float fp = proj[row + NHD + nh];
    ip = 15.f * tanhf(ip * (1.f / 15.f));
    fp = 15.f * tanhf(fp * (1.f / 15.f));
    float mx = fmaxf(ip, fp);
    float ig = expf(ip - mx);
    float fg = expf(fp - mx);
    float v = logf(fg + 1e-8f);
    for (int off = 1; off < 64; off <<= 1) {
        float u = __shfl_up(v, off);
        if (l >= off) v += u;
    }
    float last = __shfl(v, 63);
    lf[cid * CS + l] = v;
    ic[cid * CS + l] = ig;
    wC[cid * CS + l] = expf(v - last) * ig;
}

// ---------------- repack q/k/v from proj into [B,NH,NC,CS,HD] --------------
__global__ void repack_kernel(const float* __restrict__ proj, float* __restrict__ q,
                              float* __restrict__ k, float* __restrict__ v)
{
    size_t idx = (size_t)blockIdx.x * blockDim.x + threadIdx.x;
    if (idx >= (size_t)BB * NHD * NCH * CS * HDIM) return;
    int d = idx % HDIM; size_t r1 = idx / HDIM;
    int l = r1 % CS; r1 /= CS;
    int c = r1 % NCH; r1 /= NCH;
    int nh = r1 % NHD; int b = (int)(r1 / NHD);
    size_t row = ((size_t)b * SB + c * CS + l) * FUSED + 2 * NHD + nh * HDIM + d;
    q[idx] = proj[row];
    k[idx] = proj[row + HID] * 0.10206207261596577f;  // 1/sqrt(96)
    v[idx] = proj[row + 2 * HID];
}

// ---------------- per-chunk state contributions C_c[d][e], n_c[d] ----------
__global__ __launch_bounds__(256) void chunk_outer_kernel(
    const float* __restrict__ k, const float* __restrict__ v,
    const float* __restrict__ wC, float* __restrict__ Cc, float* __restrict__ nc)
{
    __shared__ float kL[CS * HDIM], vL[CS * HDIM], wL[CS];
    int cid = blockIdx.x, t = threadIdx.x;
    const float* kg = k + (size_t)cid * CS * HDIM;
    const float* vg = v + (size_t)cid * CS * HDIM;
    for (int idx = t; idx < CS * HDIM; idx += 256) { kL[idx] = kg[idx]; vL[idx] = vg[idx]; }
    if (t < CS) wL[t] = wC[cid * CS + t];
    __syncthreads();
    for (int r = 0; r < 36; ++r) {
        int flat = t + r * 256;
        int d = flat / HDIM, e = flat % HDIM;
        float acc = 0.f;
        for (int l = 0; l < CS; ++l) acc += wL[l] * vL[l * HDIM + d] * kL[l * HDIM + e];
        Cc[(size_t)cid * HDIM * HDIM + flat] = acc;
    }
    if (t < HDIM) {
        float acc = 0.f;
        for (int l = 0; l < CS; ++l) acc += wL[l] * kL[l * HDIM + t];
        nc[(size_t)cid * HDIM + t] = acc;
    }
}

// ---------------- in-place exclusive scan over chunks ----------------------
__global__ void scan_kernel(float* __restrict__ Cc, float* __restrict__ nc)
{
    int gid = blockIdx.x * blockDim.x + threadIdx.x;
    const int NCE = BB * NHD * HDIM * HDIM;   // 147456
    if (gid < NCE) {
        int bh = gid / (HDIM * HDIM);
        int ent = gid % (HDIM * HDIM);
        float run = 0.f;
        float* base = Cc + (size_t)bh * NCH * HDIM * HDIM + ent;
        for (int c = 0; c < NCH; ++c) {
            float tv = base[(size_t)c * HDIM * HDIM];
            base[(size_t)c * HDIM * HDIM] = run;
            run += tv;
        }
    } else {
        int g2 = gid - NCE;
        if (g2 < BB * NHD * HDIM) {
            int bh = g2 / HDIM, ent = g2 % HDIM;
            float run = 0.f;
            float* base = nc + (size_t)bh * NCH * HDIM + ent;
            for (int c = 0; c < NCH; ++c) {
                float tv = base[c * HDIM];
                base[c * HDIM] = run;
                run += tv;
            }
        }
    }
}

// ---------------- intra-chunk attention + state application ----------------
__global__ __launch_bounds__(256) void attn_kernel(
    const float* __restrict__ q, const float* __restrict__ k, const float* __restrict__ v,
    const float* __restrict__ lf, const float* __restrict__ ic,
    const float* __restrict__ Ci, const float* __restrict__ ni,
    float* __restrict__ hout)
{
    __shared__ float smem[12288];
    __shared__ float lfL[CS], icL[CS];
    int cid = blockIdx.x;
    int t = threadIdx.x;
    int b = cid >> 9;
    int nh = (cid >> 6) & 7;
    int c = cid & 63;
    const float* qg = q + (size_t)cid * CS * HDIM;
    const float* kg = k + (size_t)cid * CS * HDIM;
    const float* vg = v + (size_t)cid * CS * HDIM;
    for (int idx = t; idx < CS * HDIM; idx += 256) { smem[idx] = qg[idx]; smem[6144 + idx] = kg[idx]; }
    if (t < CS) { lfL[t] = lf[cid * CS + t]; icL[t] = ic[cid * CS + t]; }
    __syncthreads();
    int i = t >> 2, g = t & 3;
    float sc[16], wv[16];
    const float* qrow = smem + i * HDIM;
    #pragma unroll
    for (int jj = 0; jj < 16; ++jj) {
        int j = g + 4 * jj;
        const float* krow = smem + 6144 + j * HDIM;
        float s = 0.f;
        for (int d = 0; d < HDIM; ++d) s += qrow[d] * krow[d];
        sc[jj] = s;
        wv[jj] = (j < i) ? icL[j] * expf(lfL[i] - lfL[j]) : 0.f;
    }
    float m = -1e30f;
    #pragma unroll
    for (int jj = 0; jj < 16; ++jj) { int j = g + 4 * jj; if (j < i) m = fmaxf(m, sc[jj]); }
    m = fmaxf(m, __shfl_xor(m, 1)); m = fmaxf(m, __shfl_xor(m, 2));
    float p = 0.f;
    float ex[16];
    #pragma unroll
    for (int jj = 0; jj < 16; ++jj) {
        int j = g + 4 * jj;
        ex[jj] = (j < i) ? expf(sc[jj] - m) : 0.f;
        p += ex[jj];
    }
    p += __shfl_xor(p, 1); p += __shfl_xor(p, 2);
    float pinv = (p > 0.f) ? 1.f / p : 0.f;
    __syncthreads();                  // done reading q,k from LDS
    float* awL = smem;
    float* wL = smem + 4096;
    #pragma unroll
    for (int jj = 0; jj < 16; ++jj) {
        int j = g + 4 * jj;
        awL[i * 64 + j] = ex[jj] * pinv * wv[jj];
        wL[i * 64 + j] = wv[jj];
    }
    __syncthreads();
    float hiv[24] = {}, nia[24] = {}, hin[24] = {};
    for (int j = 0; j < CS; ++j) {
        float a = awL[i * 64 + j], ww = wL[i * 64 + j];
        const float* vrow = vg + j * HDIM + g;
        const float* krow = kg + j * HDIM + g;
        #pragma unroll
        for (int dd = 0; dd < 24; ++dd) { hiv[dd] += a * vrow[4 * dd]; nia[dd] += ww * krow[4 * dd]; }
    }
    const float* Cig = Ci + (size_t)cid * HDIM * HDIM;
    for (int e = 0; e < HDIM; ++e) {
        float qe = qg[i * HDIM + e];
        #pragma unroll
        for (int dd = 0; dd < 24; ++dd) hin[dd] += Cig[(g + 4 * dd) * HDIM + e] * qe;
    }
    const float* nig = ni + (size_t)cid * HDIM;
    float den = 0.f;
    #pragma unroll
    for (int dd = 0; dd < 24; ++dd) { int d = g + 4 * dd; den += (nig[d] + nia[dd]) * qg[i * HDIM + d]; }
    den += __shfl_xor(den, 1); den += __shfl_xor(den, 2);
    den = fmaxf(den, 1.0f);
    float dinv = 1.f / den;
    int s = c * CS + i;
    float* hrow = hout + (((size_t)b * SB + s) * NHD + nh) * HDIM;
    #pragma unroll
    for (int dd = 0; dd < 24; ++dd) hrow[g + 4 * dd] = (hin[dd] + hiv[dd]) * dinv;
}

// ---------------- LN over HID of (o*h), + skip, * silu(r_t) ----------------
__global__ __launch_bounds__(256) void ln_hid_kernel(
    const float* __restrict__ h, const float* __restrict__ o,
    const float* __restrict__ xskip, const float* __restrict__ rt,
    const float* __restrict__ w, const float* __restrict__ bb,
    float* __restrict__ out1)
{
    int row = blockIdx.x;
    size_t base = (size_t)row * HID;
    int c0 = threadIdx.x, c1 = threadIdx.x + 256, c2 = threadIdx.x + 512;
    float v0 = o[base + c0] * h[base + c0];
    float v1 = o[base + c1] * h[base + c1];
    float v2 = o[base + c2] * h[base + c2];
    float s = v0 + v1 + v2;
    float ss = v0*v0 + v1*v1 + v2*v2;
    for (int off = 32; off; off >>= 1) { s += __shfl_xor(s, off); ss += __shfl_xor(ss, off); }
    __shared__ float red[8];
    int wid = threadIdx.x >> 6;
    if ((threadIdx.x & 63) == 0) { red[wid] = s; red[4 + wid] = ss; }
    __syncthreads();
    s = red[0] + red[1] + red[2] + red[3];
    ss = red[4] + red[5] + red[6] + red[7];
    float mean = s * (1.f / HID);
    float var = ss * (1.f / HID) - mean * mean;
    float inv = rsqrtf(var + 1e-6f);
    float g0 = rt[base + c0], g1 = rt[base + c1], g2 = rt[base + c2];
    out1[base + c0] = ((v0 - mean) * inv * w[c0] + bb[c0] + xskip[base + c0]) * (g0 / (1.f + expf(-g0)));
    out1[base + c1] = ((v1 - mean) * inv * w[c1] + bb[c1] + xskip[base + c1]) * (g1 / (1.f + expf(-g1)));
    out1[base + c2] = ((v2 - mean) * inv * w[c2] + bb[c2] + xskip[base + c2]) * (g2 / (1.f + expf(-g2)));
}

extern "C" void kernel_launch(void* const* d_in, const int* in_sizes, int n_in,
                              void* d_out, int out_size, void* d_ws, size_t ws_size,
                              hipStream_t stream)
{
    const float* x       = (const float*)d_in[0];
    const float* ln_in_w = (const float*)d_in[1];
    const float* ln_in_b = (const float*)d_in[2];
    const float* ln_hid_w= (const float*)d_in[3];
    const float* ln_hid_b= (const float*)d_in[4];
    const float* up_l_w  = (const float*)d_in[5];
    const float* up_l_b  = (const float*)d_in[6];
    const float* up_r_w  = (const float*)d_in[7];
    const float* up_r_b  = (const float*)d_in[8];
    const float* down_w  = (const float*)d_in[9];
    const float* down_b  = (const float*)d_in[10];
    const float* conv_w  = (const float*)d_in[11];
    const float* conv_b  = (const float*)d_in[12];
    const float* skip_w  = (const float*)d_in[13];
    const float* skip_b  = (const float*)d_in[14];
    const float* fused_w = (const float*)d_in[15];
    const float* fused_b = (const float*)d_in[16];
    const float* wo_w    = (const float*)d_in[17];
    const float* wo_b    = (const float*)d_in[18];
    float* out = (float*)d_out;

    // -------- workspace layout (241.2 MiB total, aggressive aliasing) ------
    // region F: proj [19,005,440]   (xn aliases F[0:6.29M] in steps 1-2;
    //                                Cc aliases F[0:9.44M] after repack;
    //                                nc = F + 9,437,184)
    // region A: xt  [12,582,912]    (-> q = A[0:], k = A[6.29M:]; out1 = A later)
    // region B: xc  [12,582,912]    (-> v = B[0:], h = B[6.29M:])
    // region C: rt  [6,291,456]
    // region D: xskip [6,291,456]
    // region E: o   [6,291,456]
    // lf/ic/wC: 65,536 each
    float* ws = (float*)d_ws;
    float* proj  = ws;                          // F
    float* xn    = ws;                          // alias F (dead before proj written)
    float* Cc    = ws;                          // alias F (proj dead after repack)
    float* nc    = ws + 9437184;                // alias F tail
    float* xt    = ws + 19005440;               // A
    float* xc    = ws + 31588352;               // B
    float* rt    = ws + 44171264;               // C
    float* xskip = ws + 50462720;               // D
    float* o     = ws + 56754176;               // E
    float* lf    = ws + 63045632;
    float* ic    = ws + 63111168;
    float* wC    = ws + 63176704;               // end: 63,242,240 floats
    float* q   = xt;
    float* k   = xt + 6291456;
    float* v   = xc;
    float* h   = xc + 6291456;
    float* out1 = xt;                           // q dead after attn_kernel

    // 1. input LN
    ln_in_kernel<<<NROW, 256, 0, stream>>>(x, ln_in_w, ln_in_b, xn);
    // 2. x_t = xn @ up_l_w ; r_t = xn @ up_r_w
    gemm_kernel<<<dim3(UPD / 64, NROW / 64), 256, 0, stream>>>(xn, up_l_w, up_l_b, nullptr, xt, NROW, UPD, D_IN, 0);
    gemm_kernel<<<dim3(HID / 64, NROW / 64), 256, 0, stream>>>(xn, up_r_w, up_r_b, nullptr, rt, NROW, HID, D_IN, 0);
    // 3. causal conv + silu
    {
        size_t tot = (size_t)NROW * UPD;
        conv_kernel<<<(unsigned)((tot + 255) / 256), 256, 0, stream>>>(xt, conv_w, conv_b, xc);
    }
    // 4. skip / fused / wo gemms
    gemm_kernel<<<dim3(HID / 64, NROW / 64), 256, 0, stream>>>(xc, skip_w, skip_b, nullptr, xskip, NROW, HID, UPD, 0);
    gemm_kernel<<<dim3((FUSED + 63) / 64, NROW / 64), 256, 0, stream>>>(xc, fused_w, fused_b, nullptr, proj, NROW, FUSED, UPD, 0);
    gemm_kernel<<<dim3(HID / 64, NROW / 64), 256, 0, stream>>>(xt, wo_w, wo_b, nullptr, o, NROW, HID, UPD, 1);
    // 5. gates + scan within chunk
    gates_kernel<<<NCHUNK, 64, 0, stream>>>(proj, lf, ic, wC);
    // 6. repack q/k/v
    {
        size_t tot = (size_t)BB * NHD * NCH * CS * HDIM;
        repack_kernel<<<(unsigned)((tot + 255) / 256), 256, 0, stream>>>(proj, q, k, v);
    }
    // 7. per-chunk state contributions (into dead proj region) + exclusive scan
    chunk_outer_kernel<<<NCHUNK, 256, 0, stream>>>(k, v, wC, Cc, nc);
    {
        int tot = BB * NHD * HDIM * HDIM + BB * NHD * HDIM;
        scan_kernel<<<(tot + 255) / 256, 256, 0, stream>>>(Cc, nc);
    }
    // 8. intra-chunk attention + state application -> h in [B,S,NH,HD]
    attn_kernel<<<NCHUNK, 256, 0, stream>>>(q, k, v, lf, ic, Cc, nc, h);
    // 9. LN(o*h) + skip, * silu(r_t)
    ln_hid_kernel<<<NROW, 256, 0, stream>>>(h, o, xskip, rt, ln_hid_w, ln_hid_b, out1);
    // 10. down projection + residual x
    gemm_kernel<<<dim3(D_IN / 64, NROW / 64), 256, 0, stream>>>(out1, down_w, down_b, x, out, NROW, D_IN, HID, 0);
}

// Round 3
// 2577.316 us; speedup vs baseline: 1.5842x; 1.5842x over previous
//
#include <hip/hip_runtime.h>
#include <math.h>

#define D_IN  768
#define NHD   8
#define HDIM  96
#define HID   768
#define UPD   1536
#define FUSED 2320
#define KER   4
#define CS    64
#define NCH   64
#define SB    4096
#define BB    2
#define NROW  (BB*SB)          // 8192
#define NCHUNK (BB*NHD*NCH)    // 1024

// ---------------- LayerNorm over D_IN (input) ----------------
__global__ __launch_bounds__(256) void ln_in_kernel(
    const float* __restrict__ x, const float* __restrict__ w,
    const float* __restrict__ b, float* __restrict__ out)
{
    int row = blockIdx.x;
    size_t base = (size_t)row * D_IN;
    int c0 = threadIdx.x, c1 = threadIdx.x + 256, c2 = threadIdx.x + 512;
    float v0 = x[base + c0], v1 = x[base + c1], v2 = x[base + c2];
    float s = v0 + v1 + v2;
    float ss = v0*v0 + v1*v1 + v2*v2;
    for (int off = 32; off; off >>= 1) { s += __shfl_xor(s, off); ss += __shfl_xor(ss, off); }
    __shared__ float red[8];
    int wid = threadIdx.x >> 6;
    if ((threadIdx.x & 63) == 0) { red[wid] = s; red[4 + wid] = ss; }
    __syncthreads();
    s = red[0] + red[1] + red[2] + red[3];
    ss = red[4] + red[5] + red[6] + red[7];
    float mean = s * (1.f / D_IN);
    float var = ss * (1.f / D_IN) - mean * mean;
    float inv = rsqrtf(var + 1e-6f);
    out[base + c0] = (v0 - mean) * inv * w[c0] + b[c0];
    out[base + c1] = (v1 - mean) * inv * w[c1] + b[c1];
    out[base + c2] = (v2 - mean) * inv * w[c2] + b[c2];
}

// ---------------- generic tiled fp32 GEMM: C = act(A@B + bias) (+resid) ----
// A: [M,K] row-major, B: [K,N] row-major. act: 0=none, 1=sigmoid
__global__ __launch_bounds__(256) void gemm_kernel(
    const float* __restrict__ A, const float* __restrict__ B,
    const float* __restrict__ bias, const float* __restrict__ resid,
    float* __restrict__ C, int M, int N, int K, int act)
{
    __shared__ float As[16][68];
    __shared__ float Bs[16][64];
    int tx = threadIdx.x & 15;
    int ty = threadIdx.x >> 4;
    int m0 = blockIdx.y * 64;
    int n0 = blockIdx.x * 64;
    float acc[4][4] = {};
    for (int k0 = 0; k0 < K; k0 += 16) {
        #pragma unroll
        for (int it = 0; it < 4; ++it) {
            int idx = threadIdx.x + it * 256;
            int r = idx >> 4, c = idx & 15;
            As[c][r] = A[(size_t)(m0 + r) * K + k0 + c];
        }
        #pragma unroll
        for (int it = 0; it < 4; ++it) {
            int idx = threadIdx.x + it * 256;
            int r = idx >> 6, c = idx & 63;
            int n = n0 + c;
            Bs[r][c] = (n < N) ? B[(size_t)(k0 + r) * N + n] : 0.f;
        }
        __syncthreads();
        #pragma unroll
        for (int kk = 0; kk < 16; ++kk) {
            float a[4], bb[4];
            #pragma unroll
            for (int i = 0; i < 4; ++i) a[i] = As[kk][ty * 4 + i];
            #pragma unroll
            for (int j = 0; j < 4; ++j) bb[j] = Bs[kk][tx * 4 + j];
            #pragma unroll
            for (int i = 0; i < 4; ++i)
                #pragma unroll
                for (int j = 0; j < 4; ++j) acc[i][j] += a[i] * bb[j];
        }
        __syncthreads();
    }
    #pragma unroll
    for (int i = 0; i < 4; ++i) {
        int m = m0 + ty * 4 + i;
        #pragma unroll
        for (int j = 0; j < 4; ++j) {
            int n = n0 + tx * 4 + j;
            if (n < N) {
                float v = acc[i][j] + bias[n];
                if (act == 1) v = 1.f / (1.f + expf(-v));
                if (resid) v += resid[(size_t)m * N + n];
                C[(size_t)m * N + n] = v;
            }
        }
    }
}

// ---------------- causal depthwise conv (shared scalar kernel) + silu ------
__global__ void conv_kernel(const float* __restrict__ xt, const float* __restrict__ cw,
                            const float* __restrict__ cb, float* __restrict__ xc)
{
    size_t idx = (size_t)blockIdx.x * blockDim.x + threadIdx.x;
    if (idx >= (size_t)NROW * UPD) return;
    int ch = idx % UPD;
    int s = (int)((idx / UPD) % SB);
    int b = (int)(idx / ((size_t)UPD * SB));
    float acc = cb[0];
    #pragma unroll
    for (int j = 0; j < KER; ++j) {
        int sj = s - (KER - 1) + j;
        if (sj >= 0) acc += cw[j] * xt[((size_t)b * SB + sj) * UPD + ch];
    }
    xc[idx] = acc / (1.f + expf(-acc));   // silu
}

// ---------------- gates: softcap, exp-normalize, in-chunk log-forget scan --
__global__ __launch_bounds__(64) void gates_kernel(
    const float* __restrict__ proj, float* __restrict__ lf,
    float* __restrict__ ic, float* __restrict__ wC)
{
    int cid = blockIdx.x;
    int l = threadIdx.x;
    int b = cid >> 9;
    int nh = (cid >> 6) & 7;
    int c = cid & 63;
    int s = c * CS + l;
    size_t row = ((size_t)b * SB + s) * FUSED;
    float ip = proj[row + nh];
    float fp = proj[row + NHD + nh];
    ip = 15.f * tanhf(ip * (1.f / 15.f));
    fp = 15.f * tanhf(fp * (1.f / 15.f));
    float mx = fmaxf(ip, fp);
    float ig = expf(ip - mx);
    float fg = expf(fp - mx);
    float v = logf(fg + 1e-8f);
    for (int off = 1; off < 64; off <<= 1) {
        float u = __shfl_up(v, off);
        if (l >= off) v += u;
    }
    float last = __shfl(v, 63);
    lf[cid * CS + l] = v;
    ic[cid * CS + l] = ig;
    wC[cid * CS + l] = expf(v - last) * ig;
}

// ---------------- repack q/k/v from proj into [B,NH,NC,CS,HD] --------------
__global__ void repack_kernel(const float* __restrict__ proj, float* __restrict__ q,
                              float* __restrict__ k, float* __restrict__ v)
{
    size_t idx = (size_t)blockIdx.x * blockDim.x + threadIdx.x;
    if (idx >= (size_t)BB * NHD * NCH * CS * HDIM) return;
    int d = idx % HDIM; size_t r1 = idx / HDIM;
    int l = r1 % CS; r1 /= CS;
    int c = r1 % NCH; r1 /= NCH;
    int nh = r1 % NHD; int b = (int)(r1 / NHD);
    size_t row = ((size_t)b * SB + c * CS + l) * FUSED + 2 * NHD + nh * HDIM + d;
    q[idx] = proj[row];
    k[idx] = proj[row + HID] * 0.10206207261596577f;  // 1/sqrt(96)
    v[idx] = proj[row + 2 * HID];
}

// ---------------- per-chunk state contributions: CiT[e][d] = C^T, n_c[d] ---
// CiT[e][d] = sum_l wC[l] * k[l][e] * v[l][d]  (transposed store so the attn
// kernel's h_init loop reads rows, not strided columns)
__global__ __launch_bounds__(256) void chunk_outer_kernel(
    const float* __restrict__ k, const float* __restrict__ v,
    const float* __restrict__ wC, float* __restrict__ Cc, float* __restrict__ nc)
{
    __shared__ float kL[CS * HDIM], vL[CS * HDIM], wL[CS];
    int cid = blockIdx.x, t = threadIdx.x;
    const float* kg = k + (size_t)cid * CS * HDIM;
    const float* vg = v + (size_t)cid * CS * HDIM;
    for (int idx = t; idx < CS * HDIM; idx += 256) { kL[idx] = kg[idx]; vL[idx] = vg[idx]; }
    if (t < CS) wL[t] = wC[cid * CS + t];
    __syncthreads();
    for (int r = 0; r < 36; ++r) {
        int flat = t + r * 256;
        int e = flat / HDIM, d = flat % HDIM;
        float acc = 0.f;
        for (int l = 0; l < CS; ++l) acc += wL[l] * kL[l * HDIM + e] * vL[l * HDIM + d];
        Cc[(size_t)cid * HDIM * HDIM + flat] = acc;
    }
    if (t < HDIM) {
        float acc = 0.f;
        for (int l = 0; l < CS; ++l) acc += wL[l] * kL[l * HDIM + t];
        nc[(size_t)cid * HDIM + t] = acc;
    }
}

// ---------------- in-place exclusive scan over chunks ----------------------
__global__ void scan_kernel(float* __restrict__ Cc, float* __restrict__ nc)
{
    int gid = blockIdx.x * blockDim.x + threadIdx.x;
    const int NCE = BB * NHD * HDIM * HDIM;   // 147456
    if (gid < NCE) {
        int bh = gid / (HDIM * HDIM);
        int ent = gid % (HDIM * HDIM);
        float run = 0.f;
        float* base = Cc + (size_t)bh * NCH * HDIM * HDIM + ent;
        for (int c = 0; c < NCH; ++c) {
            float tv = base[(size_t)c * HDIM * HDIM];
            base[(size_t)c * HDIM * HDIM] = run;
            run += tv;
        }
    } else {
        int g2 = gid - NCE;
        if (g2 < BB * NHD * HDIM) {
            int bh = g2 / HDIM, ent = g2 % HDIM;
            float run = 0.f;
            float* base = nc + (size_t)bh * NCH * HDIM + ent;
            for (int c = 0; c < NCH; ++c) {
                float tv = base[c * HDIM];
                base[c * HDIM] = run;
                run += tv;
            }
        }
    }
}

// ---------------- intra-chunk attention + state application ----------------
// thread (i,g): i = row in chunk (0..63), g = d-slice (d in [24g, 24g+24))
// n_intra eliminated: sum_d n_intra[i][d] q[i][d] == sum_j w[i][j]*sc[i][j]
__global__ __launch_bounds__(256) void attn_kernel(
    const float* __restrict__ q, const float* __restrict__ k, const float* __restrict__ v,
    const float* __restrict__ lf, const float* __restrict__ ic,
    const float* __restrict__ CiT, const float* __restrict__ ni,
    float* __restrict__ hout)
{
    __shared__ float qL[64 * 100];     // stride 100: conflict-free, 16B-aligned rows
    __shared__ float kL[64 * 100];     // phase A: k rows; phase B: aw (stride 68)
    __shared__ float lfL[64], icL[64], niL[96];
    int cid = blockIdx.x, t = threadIdx.x;
    int b = cid >> 9, nh = (cid >> 6) & 7, c = cid & 63;
    const float* qg = q + (size_t)cid * (CS * HDIM);
    const float* kg = k + (size_t)cid * (CS * HDIM);
    const float* vg = v + (size_t)cid * (CS * HDIM);
    const float4* qg4 = (const float4*)qg;
    const float4* kg4 = (const float4*)kg;
    #pragma unroll
    for (int it = 0; it < 6; ++it) {
        int idx = t + it * 256;              // 0..1535 float4s
        int row = idx / 24, col = (idx % 24) * 4;
        *(float4*)&qL[row * 100 + col] = qg4[idx];
        *(float4*)&kL[row * 100 + col] = kg4[idx];
    }
    if (t < 64) { lfL[t] = lf[cid * CS + t]; icL[t] = ic[cid * CS + t]; }
    else if (t < 160) { niL[t - 64] = ni[(size_t)cid * HDIM + (t - 64)]; }
    __syncthreads();

    int i = t >> 2, g = t & 3;
    const float* qrow = qL + i * 100;
    // ---- scores sc[i][j] for j = g + 4*jj ----
    float sc[16];
    #pragma unroll
    for (int jj = 0; jj < 16; ++jj) sc[jj] = 0.f;
    for (int d4 = 0; d4 < 24; ++d4) {
        float4 qv = *(const float4*)(qrow + 4 * d4);
        #pragma unroll
        for (int jj = 0; jj < 16; ++jj) {
            float4 kv = *(const float4*)(kL + (g + 4 * jj) * 100 + 4 * d4);
            sc[jj] += qv.x * kv.x + qv.y * kv.y + qv.z * kv.z + qv.w * kv.w;
        }
    }
    // ---- decay weights ----
    float lfi = lfL[i];
    float wv[16];
    #pragma unroll
    for (int jj = 0; jj < 16; ++jj) {
        int j = g + 4 * jj;
        wv[jj] = (j < i) ? icL[j] * expf(lfi - lfL[j]) : 0.f;
    }
    // ---- denominator partial: sum_j w*sc + dot(ni, q_i) over my d-slice ----
    float den = 0.f;
    #pragma unroll
    for (int jj = 0; jj < 16; ++jj) den += wv[jj] * sc[jj];
    #pragma unroll
    for (int dd = 0; dd < 24; ++dd) {
        int d = 24 * g + dd;
        den += niL[d] * qrow[d];
    }
    // ---- softmax over masked row (j<i), within 4-lane group ----
    float m = -1e30f;
    #pragma unroll
    for (int jj = 0; jj < 16; ++jj) { int j = g + 4 * jj; if (j < i) m = fmaxf(m, sc[jj]); }
    m = fmaxf(m, __shfl_xor(m, 1)); m = fmaxf(m, __shfl_xor(m, 2));
    float p = 0.f;
    #pragma unroll
    for (int jj = 0; jj < 16; ++jj) {
        int j = g + 4 * jj;
        sc[jj] = (j < i) ? expf(sc[jj] - m) : 0.f;   // overwrite sc with exp
        p += sc[jj];
    }
    p += __shfl_xor(p, 1); p += __shfl_xor(p, 2);
    float pinv = (p > 0.f) ? 1.f / p : 0.f;
    __syncthreads();                      // all kL (k) reads done
    float* awL = kL;                      // overlay: aw matrix, stride 68
    #pragma unroll
    for (int jj = 0; jj < 16; ++jj) {
        int j = g + 4 * jj;
        awL[i * 68 + j] = sc[jj] * pinv * wv[jj];
    }
    __syncthreads();
    // ---- h = (attn*w) @ v + CiT^T-applied q, for my contiguous d-slice ----
    float4 h4[6];
    #pragma unroll
    for (int x = 0; x < 6; ++x) h4[x] = make_float4(0.f, 0.f, 0.f, 0.f);
    const float* vbase = vg + 24 * g;
    for (int j = 0; j < 64; ++j) {
        float a = awL[i * 68 + j];
        const float4* vr = (const float4*)(vbase + j * HDIM);
        #pragma unroll
        for (int x = 0; x < 6; ++x) {
            float4 vv = vr[x];
            h4[x].x += a * vv.x; h4[x].y += a * vv.y; h4[x].z += a * vv.z; h4[x].w += a * vv.w;
        }
    }
    const float* Cb = CiT + (size_t)cid * (HDIM * HDIM) + 24 * g;
    for (int e = 0; e < 96; ++e) {
        float qe = qrow[e];
        const float4* cr = (const float4*)(Cb + e * HDIM);
        #pragma unroll
        for (int x = 0; x < 6; ++x) {
            float4 cv = cr[x];
            h4[x].x += qe * cv.x; h4[x].y += qe * cv.y; h4[x].z += qe * cv.z; h4[x].w += qe * cv.w;
        }
    }
    den += __shfl_xor(den, 1); den += __shfl_xor(den, 2);
    float dinv = 1.f / fmaxf(den, 1.f);
    int s = c * CS + i;
    float4* hr4 = (float4*)(hout + (((size_t)b * SB + s) * NHD + nh) * HDIM + 24 * g);
    #pragma unroll
    for (int x = 0; x < 6; ++x) {
        float4 hv;
        hv.x = h4[x].x * dinv; hv.y = h4[x].y * dinv;
        hv.z = h4[x].z * dinv; hv.w = h4[x].w * dinv;
        hr4[x] = hv;
    }
}

// ---------------- LN over HID of (o*h), + skip, * silu(r_t) ----------------
__global__ __launch_bounds__(256) void ln_hid_kernel(
    const float* __restrict__ h, const float* __restrict__ o,
    const float* __restrict__ xskip, const float* __restrict__ rt,
    const float* __restrict__ w, const float* __restrict__ bb,
    float* __restrict__ out1)
{
    int row = blockIdx.x;
    size_t base = (size_t)row * HID;
    int c0 = threadIdx.x, c1 = threadIdx.x + 256, c2 = threadIdx.x + 512;
    float v0 = o[base + c0] * h[base + c0];
    float v1 = o[base + c1] * h[base + c1];
    float v2 = o[base + c2] * h[base + c2];
    float s = v0 + v1 + v2;
    float ss = v0*v0 + v1*v1 + v2*v2;
    for (int off = 32; off; off >>= 1) { s += __shfl_xor(s, off); ss += __shfl_xor(ss, off); }
    __shared__ float red[8];
    int wid = threadIdx.x >> 6;
    if ((threadIdx.x & 63) == 0) { red[wid] = s; red[4 + wid] = ss; }
    __syncthreads();
    s = red[0] + red[1] + red[2] + red[3];
    ss = red[4] + red[5] + red[6] + red[7];
    float mean = s * (1.f / HID);
    float var = ss * (1.f / HID) - mean * mean;
    float inv = rsqrtf(var + 1e-6f);
    float g0 = rt[base + c0], g1 = rt[base + c1], g2 = rt[base + c2];
    out1[base + c0] = ((v0 - mean) * inv * w[c0] + bb[c0] + xskip[base + c0]) * (g0 / (1.f + expf(-g0)));
    out1[base + c1] = ((v1 - mean) * inv * w[c1] + bb[c1] + xskip[base + c1]) * (g1 / (1.f + expf(-g1)));
    out1[base + c2] = ((v2 - mean) * inv * w[c2] + bb[c2] + xskip[base + c2]) * (g2 / (1.f + expf(-g2)));
}

extern "C" void kernel_launch(void* const* d_in, const int* in_sizes, int n_in,
                              void* d_out, int out_size, void* d_ws, size_t ws_size,
                              hipStream_t stream)
{
    const float* x       = (const float*)d_in[0];
    const float* ln_in_w = (const float*)d_in[1];
    const float* ln_in_b = (const float*)d_in[2];
    const float* ln_hid_w= (const float*)d_in[3];
    const float* ln_hid_b= (const float*)d_in[4];
    const float* up_l_w  = (const float*)d_in[5];
    const float* up_l_b  = (const float*)d_in[6];
    const float* up_r_w  = (const float*)d_in[7];
    const float* up_r_b  = (const float*)d_in[8];
    const float* down_w  = (const float*)d_in[9];
    const float* down_b  = (const float*)d_in[10];
    const float* conv_w  = (const float*)d_in[11];
    const float* conv_b  = (const float*)d_in[12];
    const float* skip_w  = (const float*)d_in[13];
    const float* skip_b  = (const float*)d_in[14];
    const float* fused_w = (const float*)d_in[15];
    const float* fused_b = (const float*)d_in[16];
    const float* wo_w    = (const float*)d_in[17];
    const float* wo_b    = (const float*)d_in[18];
    float* out = (float*)d_out;

    // -------- workspace layout (241.2 MiB total, aggressive aliasing) ------
    float* ws = (float*)d_ws;
    float* proj  = ws;                          // F
    float* xn    = ws;                          // alias F (dead before proj written)
    float* Cc    = ws;                          // alias F (proj dead after repack)
    float* nc    = ws + 9437184;                // alias F tail
    float* xt    = ws + 19005440;               // A
    float* xc    = ws + 31588352;               // B
    float* rt    = ws + 44171264;               // C
    float* xskip = ws + 50462720;               // D
    float* o     = ws + 56754176;               // E
    float* lf    = ws + 63045632;
    float* ic    = ws + 63111168;
    float* wC    = ws + 63176704;               // end: 63,242,240 floats
    float* q   = xt;
    float* k   = xt + 6291456;
    float* v   = xc;
    float* h   = xc + 6291456;
    float* out1 = xt;                           // q dead after attn_kernel

    // 1. input LN
    ln_in_kernel<<<NROW, 256, 0, stream>>>(x, ln_in_w, ln_in_b, xn);
    // 2. x_t = xn @ up_l_w ; r_t = xn @ up_r_w
    gemm_kernel<<<dim3(UPD / 64, NROW / 64), 256, 0, stream>>>(xn, up_l_w, up_l_b, nullptr, xt, NROW, UPD, D_IN, 0);
    gemm_kernel<<<dim3(HID / 64, NROW / 64), 256, 0, stream>>>(xn, up_r_w, up_r_b, nullptr, rt, NROW, HID, D_IN, 0);
    // 3. causal conv + silu
    {
        size_t tot = (size_t)NROW * UPD;
        conv_kernel<<<(unsigned)((tot + 255) / 256), 256, 0, stream>>>(xt, conv_w, conv_b, xc);
    }
    // 4. skip / fused / wo gemms
    gemm_kernel<<<dim3(HID / 64, NROW / 64), 256, 0, stream>>>(xc, skip_w, skip_b, nullptr, xskip, NROW, HID, UPD, 0);
    gemm_kernel<<<dim3((FUSED + 63) / 64, NROW / 64), 256, 0, stream>>>(xc, fused_w, fused_b, nullptr, proj, NROW, FUSED, UPD, 0);
    gemm_kernel<<<dim3(HID / 64, NROW / 64), 256, 0, stream>>>(xt, wo_w, wo_b, nullptr, o, NROW, HID, UPD, 1);
    // 5. gates + scan within chunk
    gates_kernel<<<NCHUNK, 64, 0, stream>>>(proj, lf, ic, wC);
    // 6. repack q/k/v
    {
        size_t tot = (size_t)BB * NHD * NCH * CS * HDIM;
        repack_kernel<<<(unsigned)((tot + 255) / 256), 256, 0, stream>>>(proj, q, k, v);
    }
    // 7. per-chunk state contributions (transposed, into dead proj) + scan
    chunk_outer_kernel<<<NCHUNK, 256, 0, stream>>>(k, v, wC, Cc, nc);
    {
        int tot = BB * NHD * HDIM * HDIM + BB * NHD * HDIM;
        scan_kernel<<<(tot + 255) / 256, 256, 0, stream>>>(Cc, nc);
    }
    // 8. intra-chunk attention + state application -> h in [B,S,NH,HD]
    attn_kernel<<<NCHUNK, 256, 0, stream>>>(q, k, v, lf, ic, Cc, nc, h);
    // 9. LN(o*h) + skip, * silu(r_t)
    ln_hid_kernel<<<NROW, 256, 0, stream>>>(h, o, xskip, rt, ln_hid_w, ln_hid_b, out1);
    // 10. down projection + residual x
    gemm_kernel<<<dim3(D_IN / 64, NROW / 64), 256, 0, stream>>>(out1, down_w, down_b, x, out, NROW, D_IN, HID, 0);
}

// Round 8
// 1607.717 us; speedup vs baseline: 2.5396x; 1.6031x over previous
//
#include <hip/hip_runtime.h>
#include <hip/hip_bf16.h>
#include <math.h>

#define D_IN  768
#define NHD   8
#define HDIM  96
#define HID   768
#define UPD   1536
#define FUSED 2320
#define KER   4
#define CS    64
#define NCH   64
#define SB    4096
#define BB    2
#define NROW  (BB*SB)          // 8192
#define NCHUNK (BB*NHD*NCH)    // 1024

using frag8 = __attribute__((ext_vector_type(8))) short;
using f32x4 = __attribute__((ext_vector_type(4))) float;

// ---- workspace offsets (floats). total 65,404,928 = 261.6 MB ----
#define O_WUPL   0
#define O_WUPR   1179648
#define O_WSKIP  1769472
#define O_WFUS   2949120
#define O_WWO    6684672
#define O_WDOWN  7864320
#define O_PROJ   8454144      // 19,005,440: xn at head; later Cc(9,437,184)+nc
#define O_XT     27459584     // 12,582,912: xt -> q,k ; out1 at head later
#define O_XC     40042496     // 12,582,912: xc -> v(head), h(+6,291,456)
#define O_RT     52625408     // 6,291,456
#define O_XSKIP  58916864     // 6,291,456
#define O_LF     65208320
#define O_IC     65273856
#define O_WC     65339392     // end 65,404,928

__device__ __forceinline__ void gld_lds16f(const float* g, float* l) {
    __builtin_amdgcn_global_load_lds(
        (const __attribute__((address_space(1))) void*)g,
        (__attribute__((address_space(3))) void*)l, 16, 0, 0);
}

// split fp32 -> bf16 hi (RNE) + mid (trunc) + lo (trunc); residual ~2^-25
__device__ __forceinline__ void split3u(float f, unsigned &H, unsigned &M, unsigned &L) {
    unsigned u = __float_as_uint(f);
    unsigned hr = (u + 0x7fffu + ((u >> 16) & 1u)) & 0xffff0000u;
    H = hr;
    float rm = f - __uint_as_float(hr);
    unsigned mr = __float_as_uint(rm) & 0xffff0000u;
    M = mr;
    float rl = rm - __uint_as_float(mr);
    L = __float_as_uint(rl) & 0xffff0000u;
}

// ---------------- fp32 weight transpose (+zero pad): w[K,N] -> wt[Npad,K] ----
__global__ __launch_bounds__(256) void tpose_f32(
    const float* __restrict__ w, float* __restrict__ wt, int K, int N)
{
    __shared__ float tile[64][65];
    int k0 = blockIdx.x * 64, n0 = blockIdx.y * 64;
    int t = threadIdx.x;
    int c = t & 63, r4 = t >> 6;
    #pragma unroll
    for (int it = 0; it < 16; ++it) {
        int r = r4 + it * 4;
        int n = n0 + c;
        tile[r][c] = (n < N) ? w[(size_t)(k0 + r) * N + n] : 0.f;
    }
    __syncthreads();
    #pragma unroll
    for (int it = 0; it < 16; ++it) {
        int nn = r4 + it * 4;
        wt[(size_t)(n0 + nn) * K + k0 + c] = tile[c][nn];
    }
}

// ---------------- LayerNorm over D_IN (fp32, round-3 verbatim) -------------
__global__ __launch_bounds__(256) void ln_in_kernel(
    const float* __restrict__ x, const float* __restrict__ w,
    const float* __restrict__ b, float* __restrict__ out)
{
    int row = blockIdx.x;
    size_t base = (size_t)row * D_IN;
    int c0 = threadIdx.x, c1 = threadIdx.x + 256, c2 = threadIdx.x + 512;
    float v0 = x[base + c0], v1 = x[base + c1], v2 = x[base + c2];
    float s = v0 + v1 + v2;
    float ss = v0*v0 + v1*v1 + v2*v2;
    for (int off = 32; off; off >>= 1) { s += __shfl_xor(s, off); ss += __shfl_xor(ss, off); }
    __shared__ float red[8];
    int wid = threadIdx.x >> 6;
    if ((threadIdx.x & 63) == 0) { red[wid] = s; red[4 + wid] = ss; }
    __syncthreads();
    s = red[0] + red[1] + red[2] + red[3];
    ss = red[4] + red[5] + red[6] + red[7];
    float mean = s * (1.f / D_IN);
    float var = ss * (1.f / D_IN) - mean * mean;
    float inv = rsqrtf(var + 1e-6f);
    out[base + c0] = (v0 - mean) * inv * w[c0] + b[c0];
    out[base + c1] = (v1 - mean) * inv * w[c1] + b[c1];
    out[base + c2] = (v2 - mean) * inv * w[c2] + b[c2];
}

// ---------------- MFMA GEMM, fp32 in/out, in-register bf16 decomposition ---
// A [M,K] fp32 row-major, BT [Npad,K] fp32 (= B^T). 128x128 tile, BK=64.
// nterms=6: hh+hm+mh+hl+lh+mm (~2^-24); nterms=3: hh+hm+mh (~2^-17).
// C = act(A@B + bias) (+resid). act 1 = sigmoid.
__global__ __launch_bounds__(256) void gemmf32s(
    const float* __restrict__ A, const float* __restrict__ BT,
    const float* __restrict__ bias, const float* __restrict__ resid,
    float* __restrict__ C, int M, int N, int K, int act, int nterms)
{
    __shared__ float Af[128 * 64];
    __shared__ float Bf[128 * 64];
    int t = threadIdx.x;
    int wave = t >> 6, lane = t & 63;
    int m0 = blockIdx.y * 128, n0 = blockIdx.x * 128;
    int wm = (wave >> 1) * 64, wn = (wave & 1) * 64;
    f32x4 acc[4][4] = {};
    int r2 = lane >> 4, c16 = lane & 15;
    for (int k0 = 0; k0 < K; k0 += 64) {
        #pragma unroll
        for (int it = 0; it < 8; ++it) {
            int rl = wave * 32 + it * 4 + r2;
            int cg = c16 ^ (rl & 15);                 // XOR-swizzled source chunk
            gld_lds16f(A  + (size_t)(m0 + rl) * K + k0 + cg * 4, &Af[wave*2048 + it*256 + lane*4]);
            gld_lds16f(BT + (size_t)(n0 + rl) * K + k0 + cg * 4, &Bf[wave*2048 + it*256 + lane*4]);
        }
        __syncthreads();
        #pragma unroll
        for (int ks = 0; ks < 2; ++ks) {
            frag8 ah[4], am[4], al[4], bh[4], bm[4], bl[4];
            int cb = ks * 8 + (lane >> 4) * 2;
            #pragma unroll
            for (int mi = 0; mi < 4; ++mi) {
                int rr = wm + mi * 16 + (lane & 15);
                const float* bp = &Af[rr * 64];
                float4 f0 = *(const float4*)&bp[((cb     ) ^ (rr & 15)) * 4];
                float4 f1 = *(const float4*)&bp[((cb + 1) ^ (rr & 15)) * 4];
                float ff[8] = {f0.x,f0.y,f0.z,f0.w,f1.x,f1.y,f1.z,f1.w};
                unsigned H[8], Mu[8], L[8];
                #pragma unroll
                for (int j = 0; j < 8; ++j) split3u(ff[j], H[j], Mu[j], L[j]);
                union { unsigned u[4]; frag8 f8; } ph, pm, pl;
                #pragma unroll
                for (int j = 0; j < 4; ++j) {
                    ph.u[j] = (H[2*j]  >> 16) | H[2*j+1];
                    pm.u[j] = (Mu[2*j] >> 16) | Mu[2*j+1];
                    pl.u[j] = (L[2*j]  >> 16) | L[2*j+1];
                }
                ah[mi] = ph.f8; am[mi] = pm.f8; al[mi] = pl.f8;
            }
            #pragma unroll
            for (int ni = 0; ni < 4; ++ni) {
                int rr = wn + ni * 16 + (lane & 15);
                const float* bp = &Bf[rr * 64];
                float4 f0 = *(const float4*)&bp[((cb     ) ^ (rr & 15)) * 4];
                float4 f1 = *(const float4*)&bp[((cb + 1) ^ (rr & 15)) * 4];
                float ff[8] = {f0.x,f0.y,f0.z,f0.w,f1.x,f1.y,f1.z,f1.w};
                unsigned H[8], Mu[8], L[8];
                #pragma unroll
                for (int j = 0; j < 8; ++j) split3u(ff[j], H[j], Mu[j], L[j]);
                union { unsigned u[4]; frag8 f8; } ph, pm, pl;
                #pragma unroll
                for (int j = 0; j < 4; ++j) {
                    ph.u[j] = (H[2*j]  >> 16) | H[2*j+1];
                    pm.u[j] = (Mu[2*j] >> 16) | Mu[2*j+1];
                    pl.u[j] = (L[2*j]  >> 16) | L[2*j+1];
                }
                bh[ni] = ph.f8; bm[ni] = pm.f8; bl[ni] = pl.f8;
            }
            #pragma unroll
            for (int mi = 0; mi < 4; ++mi)
                #pragma unroll
                for (int ni = 0; ni < 4; ++ni) {
                    acc[mi][ni] = __builtin_amdgcn_mfma_f32_16x16x32_bf16(ah[mi], bm[ni], acc[mi][ni], 0, 0, 0);
                    acc[mi][ni] = __builtin_amdgcn_mfma_f32_16x16x32_bf16(am[mi], bh[ni], acc[mi][ni], 0, 0, 0);
                    if (nterms == 6) {
                        acc[mi][ni] = __builtin_amdgcn_mfma_f32_16x16x32_bf16(ah[mi], bl[ni], acc[mi][ni], 0, 0, 0);
                        acc[mi][ni] = __builtin_amdgcn_mfma_f32_16x16x32_bf16(al[mi], bh[ni], acc[mi][ni], 0, 0, 0);
                        acc[mi][ni] = __builtin_amdgcn_mfma_f32_16x16x32_bf16(am[mi], bm[ni], acc[mi][ni], 0, 0, 0);
                    }
                    acc[mi][ni] = __builtin_amdgcn_mfma_f32_16x16x32_bf16(ah[mi], bh[ni], acc[mi][ni], 0, 0, 0);
                }
        }
        __syncthreads();
    }
    #pragma unroll
    for (int ni = 0; ni < 4; ++ni) {
        int ncol = n0 + wn + ni * 16 + (lane & 15);
        if (ncol >= N) continue;
        float bs = bias[ncol];
        #pragma unroll
        for (int mi = 0; mi < 4; ++mi) {
            #pragma unroll
            for (int r = 0; r < 4; ++r) {
                int mrow = m0 + wm + mi * 16 + (lane >> 4) * 4 + r;
                float val = acc[mi][ni][r] + bs;
                if (act == 1) val = 1.f / (1.f + expf(-val));
                if (resid) val += resid[(size_t)mrow * N + ncol];
                C[(size_t)mrow * N + ncol] = val;
            }
        }
    }
}

// ---------------- causal conv + silu (fp32, round-3 verbatim) --------------
__global__ void conv_kernel(const float* __restrict__ xt, const float* __restrict__ cw,
                            const float* __restrict__ cb, float* __restrict__ xc)
{
    size_t idx = (size_t)blockIdx.x * blockDim.x + threadIdx.x;
    if (idx >= (size_t)NROW * UPD) return;
    int ch = idx % UPD;
    int s = (int)((idx / UPD) % SB);
    int b = (int)(idx / ((size_t)UPD * SB));
    float acc = cb[0];
    #pragma unroll
    for (int j = 0; j < KER; ++j) {
        int sj = s - (KER - 1) + j;
        if (sj >= 0) acc += cw[j] * xt[((size_t)b * SB + sj) * UPD + ch];
    }
    xc[idx] = acc / (1.f + expf(-acc));
}

// ---------------- gates from proj (round-3 verbatim) -----------------------
__global__ __launch_bounds__(64) void gates_kernel(
    const float* __restrict__ proj, float* __restrict__ lf,
    float* __restrict__ ic, float* __restrict__ wC)
{
    int cid = blockIdx.x;
    int l = threadIdx.x;
    int b = cid >> 9;
    int nh = (cid >> 6) & 7;
    int c = cid & 63;
    int s = c * CS + l;
    size_t row = ((size_t)b * SB + s) * FUSED;
    float ip = proj[row + nh];
    float fp = proj[row + NHD + nh];
    ip = 15.f * tanhf(ip * (1.f / 15.f));
    fp = 15.f * tanhf(fp * (1.f / 15.f));
    float mx = fmaxf(ip, fp);
    float ig = expf(ip - mx);
    float fg = expf(fp - mx);
    float v = logf(fg + 1e-8f);
    for (int off = 1; off < 64; off <<= 1) {
        float u = __shfl_up(v, off);
        if (l >= off) v += u;
    }
    float last = __shfl(v, 63);
    lf[cid * CS + l] = v;
    ic[cid * CS + l] = ig;
    wC[cid * CS + l] = expf(v - last) * ig;
}

// ---------------- repack q/k/v from proj (round-3 verbatim) ----------------
__global__ void repack_kernel(const float* __restrict__ proj, float* __restrict__ q,
                              float* __restrict__ k, float* __restrict__ v)
{
    size_t idx = (size_t)blockIdx.x * blockDim.x + threadIdx.x;
    if (idx >= (size_t)BB * NHD * NCH * CS * HDIM) return;
    int d = idx % HDIM; size_t r1 = idx / HDIM;
    int l = r1 % CS; r1 /= CS;
    int c = r1 % NCH; r1 /= NCH;
    int nh = r1 % NHD; int b = (int)(r1 / NHD);
    size_t row = ((size_t)b * SB + c * CS + l) * FUSED + 2 * NHD + nh * HDIM + d;
    q[idx] = proj[row];
    k[idx] = proj[row + HID] * 0.10206207261596577f;
    v[idx] = proj[row + 2 * HID];
}

// ---------------- per-chunk states CiT[e][d], n_c[d] (round-3 verbatim) ----
__global__ __launch_bounds__(256) void chunk_outer_kernel(
    const float* __restrict__ k, const float* __restrict__ v,
    const float* __restrict__ wC, float* __restrict__ Cc, float* __restrict__ nc)
{
    __shared__ float kL[CS * HDIM], vL[CS * HDIM], wL[CS];
    int cid = blockIdx.x, t = threadIdx.x;
    const float* kg = k + (size_t)cid * CS * HDIM;
    const float* vg = v + (size_t)cid * CS * HDIM;
    for (int idx = t; idx < CS * HDIM; idx += 256) { kL[idx] = kg[idx]; vL[idx] = vg[idx]; }
    if (t < CS) wL[t] = wC[cid * CS + t];
    __syncthreads();
    for (int r = 0; r < 36; ++r) {
        int flat = t + r * 256;
        int e = flat / HDIM, d = flat % HDIM;
        float acc = 0.f;
        for (int l = 0; l < CS; ++l) acc += wL[l] * kL[l * HDIM + e] * vL[l * HDIM + d];
        Cc[(size_t)cid * HDIM * HDIM + flat] = acc;
    }
    if (t < HDIM) {
        float acc = 0.f;
        for (int l = 0; l < CS; ++l) acc += wL[l] * kL[l * HDIM + t];
        nc[(size_t)cid * HDIM + t] = acc;
    }
}

// ---------------- exclusive chunk scan (round-3 verbatim) ------------------
__global__ void scan_kernel(float* __restrict__ Cc, float* __restrict__ nc)
{
    int gid = blockIdx.x * blockDim.x + threadIdx.x;
    const int NCE = BB * NHD * HDIM * HDIM;
    if (gid < NCE) {
        int bh = gid / (HDIM * HDIM);
        int ent = gid % (HDIM * HDIM);
        float run = 0.f;
        float* base = Cc + (size_t)bh * NCH * HDIM * HDIM + ent;
        for (int c = 0; c < NCH; ++c) {
            float tv = base[(size_t)c * HDIM * HDIM];
            base[(size_t)c * HDIM * HDIM] = run;
            run += tv;
        }
    } else {
        int g2 = gid - NCE;
        if (g2 < BB * NHD * HDIM) {
            int bh = g2 / HDIM, ent = g2 % HDIM;
            float run = 0.f;
            float* base = nc + (size_t)bh * NCH * HDIM + ent;
            for (int c = 0; c < NCH; ++c) {
                float tv = base[c * HDIM];
                base[c * HDIM] = run;
                run += tv;
            }
        }
    }
}

// ---------------- intra-chunk attention (round-3 verbatim) -----------------
__global__ __launch_bounds__(256) void attn_kernel(
    const float* __restrict__ q, const float* __restrict__ k, const float* __restrict__ v,
    const float* __restrict__ lf, const float* __restrict__ ic,
    const float* __restrict__ CiT, const float* __restrict__ ni,
    float* __restrict__ hout)
{
    __shared__ float qL[64 * 100];
    __shared__ float kL[64 * 100];
    __shared__ float lfL[64], icL[64], niL[96];
    int cid = blockIdx.x, t = threadIdx.x;
    int b = cid >> 9, nh = (cid >> 6) & 7, c = cid & 63;
    const float* qg = q + (size_t)cid * (CS * HDIM);
    const float* kg = k + (size_t)cid * (CS * HDIM);
    const float* vg = v + (size_t)cid * (CS * HDIM);
    const float4* qg4 = (const float4*)qg;
    const float4* kg4 = (const float4*)kg;
    #pragma unroll
    for (int it = 0; it < 6; ++it) {
        int idx = t + it * 256;
        int row = idx / 24, col = (idx % 24) * 4;
        *(float4*)&qL[row * 100 + col] = qg4[idx];
        *(float4*)&kL[row * 100 + col] = kg4[idx];
    }
    if (t < 64) { lfL[t] = lf[cid * CS + t]; icL[t] = ic[cid * CS + t]; }
    else if (t < 160) { niL[t - 64] = ni[(size_t)cid * HDIM + (t - 64)]; }
    __syncthreads();

    int i = t >> 2, g = t & 3;
    const float* qrow = qL + i * 100;
    float sc[16];
    #pragma unroll
    for (int jj = 0; jj < 16; ++jj) sc[jj] = 0.f;
    for (int d4 = 0; d4 < 24; ++d4) {
        float4 qv = *(const float4*)(qrow + 4 * d4);
        #pragma unroll
        for (int jj = 0; jj < 16; ++jj) {
            float4 kv = *(const float4*)(kL + (g + 4 * jj) * 100 + 4 * d4);
            sc[jj] += qv.x * kv.x + qv.y * kv.y + qv.z * kv.z + qv.w * kv.w;
        }
    }
    float lfi = lfL[i];
    float wv[16];
    #pragma unroll
    for (int jj = 0; jj < 16; ++jj) {
        int j = g + 4 * jj;
        wv[jj] = (j < i) ? icL[j] * expf(lfi - lfL[j]) : 0.f;
    }
    float den = 0.f;
    #pragma unroll
    for (int jj = 0; jj < 16; ++jj) den += wv[jj] * sc[jj];
    #pragma unroll
    for (int dd = 0; dd < 24; ++dd) {
        int d = 24 * g + dd;
        den += niL[d] * qrow[d];
    }
    float m = -1e30f;
    #pragma unroll
    for (int jj = 0; jj < 16; ++jj) { int j = g + 4 * jj; if (j < i) m = fmaxf(m, sc[jj]); }
    m = fmaxf(m, __shfl_xor(m, 1)); m = fmaxf(m, __shfl_xor(m, 2));
    float p = 0.f;
    #pragma unroll
    for (int jj = 0; jj < 16; ++jj) {
        int j = g + 4 * jj;
        sc[jj] = (j < i) ? expf(sc[jj] - m) : 0.f;
        p += sc[jj];
    }
    p += __shfl_xor(p, 1); p += __shfl_xor(p, 2);
    float pinv = (p > 0.f) ? 1.f / p : 0.f;
    __syncthreads();
    float* awL = kL;
    #pragma unroll
    for (int jj = 0; jj < 16; ++jj) {
        int j = g + 4 * jj;
        awL[i * 68 + j] = sc[jj] * pinv * wv[jj];
    }
    __syncthreads();
    float4 h4[6];
    #pragma unroll
    for (int x = 0; x < 6; ++x) h4[x] = make_float4(0.f, 0.f, 0.f, 0.f);
    const float* vbase = vg + 24 * g;
    for (int j = 0; j < 64; ++j) {
        float a = awL[i * 68 + j];
        const float4* vr = (const float4*)(vbase + j * HDIM);
        #pragma unroll
        for (int x = 0; x < 6; ++x) {
            float4 vv = vr[x];
            h4[x].x += a * vv.x; h4[x].y += a * vv.y; h4[x].z += a * vv.z; h4[x].w += a * vv.w;
        }
    }
    const float* Cb = CiT + (size_t)cid * (HDIM * HDIM) + 24 * g;
    for (int e = 0; e < 96; ++e) {
        float qe = qrow[e];
        const float4* cr = (const float4*)(Cb + e * HDIM);
        #pragma unroll
        for (int x = 0; x < 6; ++x) {
            float4 cv = cr[x];
            h4[x].x += qe * cv.x; h4[x].y += qe * cv.y; h4[x].z += qe * cv.z; h4[x].w += qe * cv.w;
        }
    }
    den += __shfl_xor(den, 1); den += __shfl_xor(den, 2);
    float dinv = 1.f / fmaxf(den, 1.f);
    int s = c * CS + i;
    float4* hr4 = (float4*)(hout + (((size_t)b * SB + s) * NHD + nh) * HDIM + 24 * g);
    #pragma unroll
    for (int x = 0; x < 6; ++x) {
        float4 hv;
        hv.x = h4[x].x * dinv; hv.y = h4[x].y * dinv;
        hv.z = h4[x].z * dinv; hv.w = h4[x].w * dinv;
        hr4[x] = hv;
    }
}

// ---------------- LN(o*h)+skip, *silu(rt) (fp32, round-3 verbatim) ---------
__global__ __launch_bounds__(256) void ln_hid_kernel(
    const float* __restrict__ h, const float* __restrict__ o,
    const float* __restrict__ xskip, const float* __restrict__ rt,
    const float* __restrict__ w, const float* __restrict__ bb,
    float* __restrict__ out1)
{
    int row = blockIdx.x;
    size_t base = (size_t)row * HID;
    int c0 = threadIdx.x, c1 = threadIdx.x + 256, c2 = threadIdx.x + 512;
    float v0 = o[base + c0] * h[base + c0];
    float v1 = o[base + c1] * h[base + c1];
    float v2 = o[base + c2] * h[base + c2];
    float s = v0 + v1 + v2;
    float ss = v0*v0 + v1*v1 + v2*v2;
    for (int off = 32; off; off >>= 1) { s += __shfl_xor(s, off); ss += __shfl_xor(ss, off); }
    __shared__ float red[8];
    int wid = threadIdx.x >> 6;
    if ((threadIdx.x & 63) == 0) { red[wid] = s; red[4 + wid] = ss; }
    __syncthreads();
    s = red[0] + red[1] + red[2] + red[3];
    ss = red[4] + red[5] + red[6] + red[7];
    float mean = s * (1.f / HID);
    float var = ss * (1.f / HID) - mean * mean;
    float inv = rsqrtf(var + 1e-6f);
    float g0 = rt[base + c0], g1 = rt[base + c1], g2 = rt[base + c2];
    out1[base + c0] = ((v0 - mean) * inv * w[c0] + bb[c0] + xskip[base + c0]) * (g0 / (1.f + expf(-g0)));
    out1[base + c1] = ((v1 - mean) * inv * w[c1] + bb[c1] + xskip[base + c1]) * (g1 / (1.f + expf(-g1)));
    out1[base + c2] = ((v2 - mean) * inv * w[c2] + bb[c2] + xskip[base + c2]) * (g2 / (1.f + expf(-g2)));
}

extern "C" void kernel_launch(void* const* d_in, const int* in_sizes, int n_in,
                              void* d_out, int out_size, void* d_ws, size_t ws_size,
                              hipStream_t stream)
{
    const float* x       = (const float*)d_in[0];
    const float* ln_in_w = (const float*)d_in[1];
    const float* ln_in_b = (const float*)d_in[2];
    const float* ln_hid_w= (const float*)d_in[3];
    const float* ln_hid_b= (const float*)d_in[4];
    const float* up_l_w  = (const float*)d_in[5];
    const float* up_l_b  = (const float*)d_in[6];
    const float* up_r_w  = (const float*)d_in[7];
    const float* up_r_b  = (const float*)d_in[8];
    const float* down_w  = (const float*)d_in[9];
    const float* down_b  = (const float*)d_in[10];
    const float* conv_w  = (const float*)d_in[11];
    const float* conv_b  = (const float*)d_in[12];
    const float* skip_w  = (const float*)d_in[13];
    const float* skip_b  = (const float*)d_in[14];
    const float* fused_w = (const float*)d_in[15];
    const float* fused_b = (const float*)d_in[16];
    const float* wo_w    = (const float*)d_in[17];
    const float* wo_b    = (const float*)d_in[18];
    float* out = (float*)d_out;

    float* ws = (float*)d_ws;
    float* wupl  = ws + O_WUPL;
    float* wupr  = ws + O_WUPR;
    float* wskip = ws + O_WSKIP;
    float* wfus  = ws + O_WFUS;
    float* wwo   = ws + O_WWO;
    float* wdown = ws + O_WDOWN;
    float* proj  = ws + O_PROJ;
    float* xn    = ws + O_PROJ;            // alias: head of proj, dead before fused GEMM
    float* Cc    = ws + O_PROJ;            // alias: proj dead after repack
    float* nc    = ws + O_PROJ + 9437184;
    float* xt    = ws + O_XT;
    float* q     = ws + O_XT;              // alias after wo consumes xt
    float* k     = ws + O_XT + 6291456;
    float* out1  = ws + O_XT;              // alias after attn consumes q
    float* xc    = ws + O_XC;
    float* v     = ws + O_XC;              // alias after fused consumes xc
    float* h     = ws + O_XC + 6291456;
    float* rt    = ws + O_RT;
    float* xskip = ws + O_XSKIP;
    float* o     = (float*)d_out;          // scratch until final GEMM overwrites
    float* lf    = ws + O_LF;
    float* ic    = ws + O_IC;
    float* wC    = ws + O_WC;

    // 0. fp32 weight transposes (+pad fused to 2432)
    tpose_f32<<<dim3(12, 24), 256, 0, stream>>>(up_l_w, wupl, 768, 1536);
    tpose_f32<<<dim3(12, 12), 256, 0, stream>>>(up_r_w, wupr, 768, 768);
    tpose_f32<<<dim3(24, 12), 256, 0, stream>>>(skip_w, wskip, 1536, 768);
    tpose_f32<<<dim3(24, 38), 256, 0, stream>>>(fused_w, wfus, 1536, 2320);
    tpose_f32<<<dim3(24, 12), 256, 0, stream>>>(wo_w, wwo, 1536, 768);
    tpose_f32<<<dim3(12, 12), 256, 0, stream>>>(down_w, wdown, 768, 768);
    // 1. input LN -> xn fp32
    ln_in_kernel<<<NROW, 256, 0, stream>>>(x, ln_in_w, ln_in_b, xn);
    // 2. up projections: x_t (6-term, recurrence path), r_t (3-term)
    gemmf32s<<<dim3(12, 64), 256, 0, stream>>>(xn, wupl, up_l_b, nullptr, xt, NROW, UPD, D_IN, 0, 6);
    gemmf32s<<<dim3(6, 64), 256, 0, stream>>>(xn, wupr, up_r_b, nullptr, rt, NROW, HID, D_IN, 0, 3);
    // 3. causal conv + silu -> xc fp32
    {
        size_t tot = (size_t)NROW * UPD;
        conv_kernel<<<(unsigned)((tot + 255) / 256), 256, 0, stream>>>(xt, conv_w, conv_b, xc);
    }
    // 4. wo (3-term, consumes xt) -> o (in d_out); skip (3-term); fused (6-term) -> proj
    gemmf32s<<<dim3(6, 64), 256, 0, stream>>>(xt, wwo, wo_b, nullptr, o, NROW, HID, UPD, 1, 3);
    gemmf32s<<<dim3(6, 64), 256, 0, stream>>>(xc, wskip, skip_b, nullptr, xskip, NROW, HID, UPD, 0, 3);
    gemmf32s<<<dim3(19, 64), 256, 0, stream>>>(xc, wfus, fused_b, nullptr, proj, NROW, FUSED, UPD, 0, 6);
    // 5. gates from proj
    gates_kernel<<<NCHUNK, 64, 0, stream>>>(proj, lf, ic, wC);
    // 6. repack q/k/v from proj (into dead xt / xc regions)
    {
        size_t tot = (size_t)BB * NHD * NCH * CS * HDIM;
        repack_kernel<<<(unsigned)((tot + 255) / 256), 256, 0, stream>>>(proj, q, k, v);
    }
    // 7. per-chunk states (into dead proj) + exclusive scan
    chunk_outer_kernel<<<NCHUNK, 256, 0, stream>>>(k, v, wC, Cc, nc);
    {
        int tot = BB * NHD * HDIM * HDIM + BB * NHD * HDIM;
        scan_kernel<<<(tot + 255) / 256, 256, 0, stream>>>(Cc, nc);
    }
    // 8. intra-chunk attention -> h fp32
    attn_kernel<<<NCHUNK, 256, 0, stream>>>(q, k, v, lf, ic, Cc, nc, h);
    // 9. LN(o*h) + skip, * silu(rt) -> out1 fp32 (over dead q)
    ln_hid_kernel<<<NROW, 256, 0, stream>>>(h, o, xskip, rt, ln_hid_w, ln_hid_b, out1);
    // 10. down (3-term) + residual x -> out (overwrites o scratch)
    gemmf32s<<<dim3(6, 64), 256, 0, stream>>>(out1, wdown, down_b, x, out, NROW, D_IN, HID, 0, 3);
}